// Round 1
// baseline (422.715 us; speedup 1.0000x reference)
//
#include <hip/hip_runtime.h>

// VQEmbedding forward (TRAINING=True):
//   z_e_x [32,256,64,64] f32, codebook [512,256] f32, labels [32] i32
//   out = concat(z_q_x, z_q_x_bar), each [32,256,64,64] f32 — both equal
//   codebook[argmin] in the forward pass.
//
// Reference arithmetic emulated bit-exactly (same as prior passing rounds):
//   - dot: ascending-d fp32 FMA chain per (point, code)  (== sgemm)
//   - in_sqr: fp64 ascending-d fma -> fp32
//   - cb_sqr: fp64 -> fp32
//   - dist = fmaf(-2, acc, fl(insq + cbs_k)); strict < ascending k == first-index tie
//
// R4 restructure: 1 point/lane forced scalar dword x-loads (4x duplicated
// across waves) and scalar dword stores. Now each lane owns 4 consecutive hw
// points: block = 256 points, wave w still owns 13 codes (wave-uniform kbase
// -> s_load SGPR operand), x loads are dwordx4, epilogue stores are dwordx4.
// Same FLOPs, ~4x fewer vmem/store instructions, 4x ILP on the FMA chains.
// 512 blocks co-resident (2 waves/SIMD); stores are fire-and-forget.

#define D       256
#define KCODES  512
#define HW      4096
#define BATCH   32
#define NPTS    (BATCH * HW)   // 131072
#define WPW     13             // codes per wave (4*13 = 52 >= max class size 51)
#define PTS     256            // points per block

__constant__ int c_cls_start[11] = {0, 51, 101, 151, 201, 251, 301, 352, 402, 452, 502};

// Prep: cbT[d][k] = cb[k][d]  (per-d class slice contiguous -> scalar loads),
//       cbs[k] = fl32( fp64 sum_d cb[k][d]^2 )
__global__ __launch_bounds__(256) void prep_kernel(const float* __restrict__ cb,
                                                   float* __restrict__ cbT,
                                                   float* __restrict__ cbs) {
    const int k = blockIdx.x;   // 0..511
    const int d = threadIdx.x;  // 0..255
    float v = cb[k * D + d];
    cbT[(size_t)d * KCODES + k] = v;
    __shared__ double red[256];
    red[d] = (double)v * (double)v;
    __syncthreads();
    for (int s = 128; s > 0; s >>= 1) {
        if (d < s) red[d] += red[d + s];
        __syncthreads();
    }
    if (d == 0) cbs[k] = (float)red[0];
}

__global__ __launch_bounds__(256) void vq_kernel(const float* __restrict__ z,
                                                 const int* __restrict__ labels,
                                                 const float* __restrict__ cbT,
                                                 const float* __restrict__ cbs,
                                                 float* __restrict__ out) {
    const int lane = threadIdx.x & 63;
    const int w    = __builtin_amdgcn_readfirstlane(threadIdx.x >> 6);  // wave 0..3
    const int b    = blockIdx.x >> 4;                 // 16 blocks per image
    const int hw0  = (blockIdx.x & 15) << 8;          // 256-point tile base
    const int p4   = hw0 | (lane << 2);               // this lane's 4 points
    const int lab  = __builtin_amdgcn_readfirstlane(labels[b]);
    const int c0   = c_cls_start[lab];
    const int cnt  = c_cls_start[lab + 1] - c0;       // 50 or 51
    const int kbase = c0 + w * WPW;                   // wave-uniform (SGPR)
    const int myn   = min(WPW, cnt - w * WPW);        // 13,13,13,{11|12}

    const float* __restrict__ xp = z + (size_t)b * (D * HW) + p4;  // x4[d] = xp[d*HW..+3]

    float acc[WPW][4];
#pragma unroll
    for (int j = 0; j < WPW; ++j)
#pragma unroll
        for (int p = 0; p < 4; ++p) acc[j][p] = 0.0f;

    double xsq[4] = {0.0, 0.0, 0.0, 0.0};  // ||x||^2 in fp64, ascending d

    // x prefetch pipeline, depth 4 (each entry = 4 points at one d)
    float4 xb[4];
#pragma unroll
    for (int i = 0; i < 4; ++i) xb[i] = *(const float4*)(xp + (size_t)i * HW);

    for (int d = 0; d < D; d += 4) {
        float4 xn[4];
#pragma unroll
        for (int i = 0; i < 4; ++i) {
            int dn = (d + 4 + i) & (D - 1);  // wrap on last chunk (harmless reload)
            xn[i] = *(const float4*)(xp + (size_t)dn * HW);
        }
#pragma unroll
        for (int i = 0; i < 4; ++i) {
            // wave-uniform address -> scalar loads, SGPR FMA operand
            const float* __restrict__ wd = cbT + (size_t)(d + i) * KCODES + kbase;
            const float4 x = xb[i];
            xsq[0] = fma((double)x.x, (double)x.x, xsq[0]);
            xsq[1] = fma((double)x.y, (double)x.y, xsq[1]);
            xsq[2] = fma((double)x.z, (double)x.z, xsq[2]);
            xsq[3] = fma((double)x.w, (double)x.w, xsq[3]);
#pragma unroll
            for (int j = 0; j < WPW; ++j) {
                const float c = wd[j];
                acc[j][0] = fmaf(x.x, c, acc[j][0]);  // ascending-d fp32 chain
                acc[j][1] = fmaf(x.y, c, acc[j][1]);
                acc[j][2] = fmaf(x.z, c, acc[j][2]);
                acc[j][3] = fmaf(x.w, c, acc[j][3]);
            }
        }
#pragma unroll
        for (int i = 0; i < 4; ++i) xb[i] = xn[i];
    }

    // Emulated reference distance; local argmin over this wave's 13 codes
    __shared__ float sd[4][PTS];
    __shared__ int   si[4][PTS];
#pragma unroll
    for (int p = 0; p < 4; ++p) {
        const float insq = (float)xsq[p];
        float best = __builtin_inff();
        int bi = kbase;
#pragma unroll
        for (int j = 0; j < WPW; ++j) {
            if (j < myn) {
                float T    = insq + cbs[kbase + j];    // fp32 add, RNE
                float dist = fmaf(-2.0f, acc[j][p], T);  // == fl(T - 2*acc)
                if (dist < best) { best = dist; bi = kbase + j; }
            }
        }
        sd[w][(lane << 2) + p] = best;
        si[w][(lane << 2) + p] = bi;
    }
    __syncthreads();

    // Cross-wave argmin (ascending w + strict < == lowest-index tie-break)
    __shared__ int fidx[PTS];
    {
        const int pi = threadIdx.x;  // one point per thread
        float fb = sd[0][pi];
        int   fi = si[0][pi];
#pragma unroll
        for (int w2 = 1; w2 < 4; ++w2) {
            float dv = sd[w2][pi];
            if (dv < fb) { fb = dv; fi = si[w2][pi]; }
        }
        fidx[pi] = fi;
    }
    __syncthreads();

    // Epilogue: out0 = out1 = codebook[fidx]; wave w writes d in [64w, 64w+64),
    // each lane writes its 4 points as one dwordx4 per output per d.
    int f0 = fidx[(lane << 2) + 0];
    int f1 = fidx[(lane << 2) + 1];
    int f2 = fidx[(lane << 2) + 2];
    int f3 = fidx[(lane << 2) + 3];

    float* __restrict__ o0 = out + (size_t)b * (D * HW) + p4;
    float* __restrict__ o1 = o0 + (size_t)NPTS * D;
    const int d0 = w * 64;
    const float* __restrict__ cbd = cbT + (size_t)d0 * KCODES;
    for (int d = d0; d < d0 + 64; ++d) {
        float4 v;  // gathers land in a 204 B class window -> L1
        v.x = cbd[f0];
        v.y = cbd[f1];
        v.z = cbd[f2];
        v.w = cbd[f3];
        *(float4*)(o0 + (size_t)d * HW) = v;
        *(float4*)(o1 + (size_t)d * HW) = v;
        cbd += KCODES;
    }
}

extern "C" void kernel_launch(void* const* d_in, const int* in_sizes, int n_in,
                              void* d_out, int out_size, void* d_ws, size_t ws_size,
                              hipStream_t stream) {
    const float* z      = (const float*)d_in[0];
    const float* cb     = (const float*)d_in[1];
    const int*   labels = (const int*)d_in[2];
    float* out = (float*)d_out;

    float* cbT = (float*)d_ws;              // 256*512 f32 = 512 KB
    float* cbs = cbT + (size_t)D * KCODES;  // 512 f32

    hipLaunchKernelGGL(prep_kernel, dim3(KCODES), dim3(D), 0, stream, cb, cbT, cbs);
    hipLaunchKernelGGL(vq_kernel, dim3(NPTS / PTS), dim3(256), 0, stream,
                       z, labels, cbT, cbs, out);
}